// Round 1
// baseline (128.983 us; speedup 1.0000x reference)
//
#include <hip/hip_runtime.h>
#include <hip/hip_bf16.h>

#define BB 8
#define NN 8192
#define DD 128
#define HH 8
#define KQ 64

// ---------- Stage 1: partial Gram matrices  part[b][s] = X_chunk^T X_chunk ----------
__global__ __launch_bounds__(256) void gram_partial(
    const float* __restrict__ x, float* __restrict__ part, int rowsPer) {
  const int s = blockIdx.x, b = blockIdx.y, t = threadIdx.x;
  __shared__ float xs[8][DD];
  const float* xb = x + ((size_t)b * NN + (size_t)s * rowsPer) * DD;
  const int rt = (t >> 4) * 8;   // row-tile base within 128
  const int ct = (t & 15) * 8;   // col-tile base within 128
  float acc[8][8];
#pragma unroll
  for (int i = 0; i < 8; ++i)
#pragma unroll
    for (int j = 0; j < 8; ++j) acc[i][j] = 0.f;

  for (int r0 = 0; r0 < rowsPer; r0 += 8) {
    __syncthreads();
    ((float4*)&xs[0][0])[t] = ((const float4*)(xb + (size_t)r0 * DD))[t];
    __syncthreads();
#pragma unroll
    for (int r = 0; r < 8; ++r) {
      float xr[8], xc[8];
#pragma unroll
      for (int i = 0; i < 8; ++i) xr[i] = xs[r][rt + i];
#pragma unroll
      for (int j = 0; j < 8; ++j) xc[j] = xs[r][ct + j];
#pragma unroll
      for (int i = 0; i < 8; ++i)
#pragma unroll
        for (int j = 0; j < 8; ++j)
          acc[i][j] = fmaf(xr[i], xc[j], acc[i][j]);
    }
  }
  float* g = part + ((size_t)b * gridDim.x + s) * (DD * DD);
#pragma unroll
  for (int i = 0; i < 8; ++i) {
    float4 v0 = {acc[i][0], acc[i][1], acc[i][2], acc[i][3]};
    float4 v1 = {acc[i][4], acc[i][5], acc[i][6], acc[i][7]};
    float4* dst = (float4*)(g + (size_t)(rt + i) * DD + ct);
    dst[0] = v0;
    dst[1] = v1;
  }
}

// ---------- Stage 2: reduce partials -> G[b] ----------
__global__ __launch_bounds__(256) void gram_reduce(
    const float* __restrict__ part, float* __restrict__ G, int split) {
  const int b = blockIdx.y;
  const size_t base = (size_t)blockIdx.x * 1024 + (size_t)threadIdx.x * 4;
  const float* p = part + (size_t)b * split * (DD * DD) + base;
  float4 s = {0.f, 0.f, 0.f, 0.f};
  for (int i = 0; i < split; ++i) {
    float4 v = *(const float4*)(p + (size_t)i * (DD * DD));
    s.x += v.x; s.y += v.y; s.z += v.z; s.w += v.w;
  }
  *(float4*)(G + (size_t)b * (DD * DD) + base) = s;
}

// ---------- Stage 3a: T1[b,h] = Wk[h] @ G[b]   ([64 x 128]) ----------
__global__ __launch_bounds__(256) void t1_kernel(
    const float* __restrict__ G, const float* __restrict__ Wk,
    float* __restrict__ T1) {
  const int h = blockIdx.x >> 2, ds = blockIdx.x & 3, b = blockIdx.y;
  const int t = threadIdx.x;
  const int dsbase = ds * 32;
  __shared__ float Wk_t[DD][65];  // [d][k], padded (bank-free column reads)
  __shared__ float Gsl[DD][32];   // [d][d2-slice]
#pragma unroll
  for (int c = 0; c < 32; ++c) {
    int i = t + c * 256;
    Wk_t[i & 127][i >> 7] = Wk[(size_t)h * KQ * DD + i];
  }
#pragma unroll
  for (int c = 0; c < 4; ++c) {
    int f = t + c * 256;
    int d = f >> 3, c4 = (f & 7) * 4;
    *(float4*)&Gsl[d][c4] =
        *(const float4*)(G + (size_t)b * DD * DD + (size_t)d * DD + dsbase + c4);
  }
  __syncthreads();
  const int k = t >> 2, q = (t & 3) * 8;
  float acc[8];
#pragma unroll
  for (int i = 0; i < 8; ++i) acc[i] = 0.f;
#pragma unroll 4
  for (int d = 0; d < DD; ++d) {
    float wk = Wk_t[d][k];
    float4 g0 = *(const float4*)&Gsl[d][q];
    float4 g1 = *(const float4*)&Gsl[d][q + 4];
    acc[0] = fmaf(wk, g0.x, acc[0]);
    acc[1] = fmaf(wk, g0.y, acc[1]);
    acc[2] = fmaf(wk, g0.z, acc[2]);
    acc[3] = fmaf(wk, g0.w, acc[3]);
    acc[4] = fmaf(wk, g1.x, acc[4]);
    acc[5] = fmaf(wk, g1.y, acc[5]);
    acc[6] = fmaf(wk, g1.z, acc[6]);
    acc[7] = fmaf(wk, g1.w, acc[7]);
  }
  float* dst = T1 + (((size_t)b * HH + h) * KQ + k) * DD + dsbase + q;
  float4 v0 = {acc[0], acc[1], acc[2], acc[3]};
  float4 v1 = {acc[4], acc[5], acc[6], acc[7]};
  ((float4*)dst)[0] = v0;
  ((float4*)dst)[1] = v1;
}

// ---------- Stage 3b: T2[b,h] = T1[b,h] @ Wv[h]^T   ([64 x 128]) ----------
__global__ __launch_bounds__(256) void t2_kernel(
    const float* __restrict__ T1, const float* __restrict__ Wv,
    float* __restrict__ T2) {
  const int h = blockIdx.x >> 2, es = blockIdx.x & 3, b = blockIdx.y;
  const int t = threadIdx.x;
  const int ebase = es * 32;
  __shared__ float T1_t[DD][65];  // [d2][k]
  __shared__ float Wv_t[DD][36];  // [d2][e-slice], stride 36 (16B-aligned rows)
  const float* t1src = T1 + ((size_t)b * HH + h) * KQ * DD;
#pragma unroll
  for (int c = 0; c < 32; ++c) {
    int i = t + c * 256;
    T1_t[i & 127][i >> 7] = t1src[i];
  }
#pragma unroll
  for (int c = 0; c < 16; ++c) {
    int i = t + c * 256;
    int e = i >> 7, d2 = i & 127;
    Wv_t[d2][e] = Wv[((size_t)h * DD + ebase + e) * DD + d2];
  }
  __syncthreads();
  const int k = t >> 2, q = (t & 3) * 8;
  float acc[8];
#pragma unroll
  for (int i = 0; i < 8; ++i) acc[i] = 0.f;
#pragma unroll 4
  for (int d2 = 0; d2 < DD; ++d2) {
    float t1 = T1_t[d2][k];
    float4 w0 = *(const float4*)&Wv_t[d2][q];
    float4 w1 = *(const float4*)&Wv_t[d2][q + 4];
    acc[0] = fmaf(t1, w0.x, acc[0]);
    acc[1] = fmaf(t1, w0.y, acc[1]);
    acc[2] = fmaf(t1, w0.z, acc[2]);
    acc[3] = fmaf(t1, w0.w, acc[3]);
    acc[4] = fmaf(t1, w1.x, acc[4]);
    acc[5] = fmaf(t1, w1.y, acc[5]);
    acc[6] = fmaf(t1, w1.z, acc[6]);
    acc[7] = fmaf(t1, w1.w, acc[7]);
  }
  float* dst = T2 + (((size_t)b * HH + h) * KQ + k) * DD + ebase + q;
  float4 v0 = {acc[0], acc[1], acc[2], acc[3]};
  float4 v1 = {acc[4], acc[5], acc[6], acc[7]};
  ((float4*)dst)[0] = v0;
  ((float4*)dst)[1] = v1;
}

// ---------- Stage 3c: Mp[b,hs] = Wq_flat[hk-slice]^T @ T2_flat[b][hk-slice] ----------
__global__ __launch_bounds__(256) void mpart_kernel(
    const float* __restrict__ T2, const float* __restrict__ Wq,
    float* __restrict__ Mp) {
  const int es2 = blockIdx.x >> 1, hs = blockIdx.x & 1, b = blockIdx.y;
  const int t = threadIdx.x;
  const int e2 = es2 * 16, hkbase = hs * 256;
  __shared__ float T2s[256][20];  // [hk][e-slice], stride 20 (80B, 16B-aligned)
#pragma unroll
  for (int c = 0; c < 4; ++c) {
    int f = t + c * 256;
    int r = f >> 2, c4 = (f & 3) * 4;
    *(float4*)&T2s[r][c4] =
        *(const float4*)(T2 + ((size_t)b * 512 + hkbase + r) * DD + e2 + c4);
  }
  __syncthreads();
  const int d = t >> 1, eh = (t & 1) * 8;
  float acc[8];
#pragma unroll
  for (int i = 0; i < 8; ++i) acc[i] = 0.f;
#pragma unroll 4
  for (int hk = 0; hk < 256; ++hk) {
    float wq = Wq[(size_t)(hkbase + hk) * DD + d];
    float4 a0 = *(const float4*)&T2s[hk][eh];
    float4 a1 = *(const float4*)&T2s[hk][eh + 4];
    acc[0] = fmaf(wq, a0.x, acc[0]);
    acc[1] = fmaf(wq, a0.y, acc[1]);
    acc[2] = fmaf(wq, a0.z, acc[2]);
    acc[3] = fmaf(wq, a0.w, acc[3]);
    acc[4] = fmaf(wq, a1.x, acc[4]);
    acc[5] = fmaf(wq, a1.y, acc[5]);
    acc[6] = fmaf(wq, a1.z, acc[6]);
    acc[7] = fmaf(wq, a1.w, acc[7]);
  }
  float* dst = Mp + ((size_t)b * 2 + hs) * (DD * DD) + (size_t)d * DD + e2 + eh;
  float4 v0 = {acc[0], acc[1], acc[2], acc[3]};
  float4 v1 = {acc[4], acc[5], acc[6], acc[7]};
  ((float4*)dst)[0] = v0;
  ((float4*)dst)[1] = v1;
}

// ---------- Stage 3d: M[b] = Mp[b][0] + Mp[b][1] ----------
__global__ __launch_bounds__(256) void m_reduce(
    const float* __restrict__ Mp, float* __restrict__ M) {
  const int b = blockIdx.y;
  const size_t base = (size_t)blockIdx.x * 1024 + (size_t)threadIdx.x * 4;
  float4 a = *(const float4*)(Mp + ((size_t)b * 2 + 0) * (DD * DD) + base);
  float4 c = *(const float4*)(Mp + ((size_t)b * 2 + 1) * (DD * DD) + base);
  float4 s = {a.x + c.x, a.y + c.y, a.z + c.z, a.w + c.w};
  *(float4*)(M + (size_t)b * (DD * DD) + base) = s;
}

// ---------- Stage 4: out[b] = X[b] @ M[b] ----------
__global__ __launch_bounds__(256) void out_mm(
    const float* __restrict__ x, const float* __restrict__ M,
    float* __restrict__ out) {
  const int b = blockIdx.y, t = threadIdx.x;
  const size_t rowbase = (size_t)blockIdx.x * 128;
  __shared__ float Ms[DD][DD];    // 64 KB
  __shared__ float xsb[32][DD];   // 16 KB
  {
    const float4* src = (const float4*)(M + (size_t)b * DD * DD);
    float4* dst = (float4*)&Ms[0][0];
#pragma unroll
    for (int c = 0; c < 16; ++c) dst[t + c * 256] = src[t + c * 256];
  }
  const float* xb = x + ((size_t)b * NN + rowbase) * DD;
  float* ob = out + ((size_t)b * NN + rowbase) * DD;
  const int e4 = (t & 31) * 4;
  const int rg = (t >> 5) * 4;
  for (int c = 0; c < 4; ++c) {
    __syncthreads();
    {
      const float4* src = (const float4*)(xb + (size_t)c * 32 * DD);
      float4* dst = (float4*)&xsb[0][0];
#pragma unroll
      for (int i = 0; i < 4; ++i) dst[t + i * 256] = src[t + i * 256];
    }
    __syncthreads();
    float acc[4][4];
#pragma unroll
    for (int i = 0; i < 4; ++i)
#pragma unroll
      for (int j = 0; j < 4; ++j) acc[i][j] = 0.f;
#pragma unroll 2
    for (int d = 0; d < DD; ++d) {
      float4 m = *(const float4*)&Ms[d][e4];
#pragma unroll
      for (int rr = 0; rr < 4; ++rr) {
        float xv = xsb[rg + rr][d];
        acc[rr][0] = fmaf(xv, m.x, acc[rr][0]);
        acc[rr][1] = fmaf(xv, m.y, acc[rr][1]);
        acc[rr][2] = fmaf(xv, m.z, acc[rr][2]);
        acc[rr][3] = fmaf(xv, m.w, acc[rr][3]);
      }
    }
#pragma unroll
    for (int rr = 0; rr < 4; ++rr) {
      float4 v = {acc[rr][0], acc[rr][1], acc[rr][2], acc[rr][3]};
      *(float4*)(ob + (size_t)(c * 32 + rg + rr) * DD + e4) = v;
    }
  }
}

extern "C" void kernel_launch(void* const* d_in, const int* in_sizes, int n_in,
                              void* d_out, int out_size, void* d_ws, size_t ws_size,
                              hipStream_t stream) {
  const float* x  = (const float*)d_in[0];
  const float* Wk = (const float*)d_in[1];
  const float* Wq = (const float*)d_in[2];
  const float* Wv = (const float*)d_in[3];
  float* out = (float*)d_out;
  float* ws  = (float*)d_ws;

  const size_t off_G    = 0;
  const size_t off_M    = off_G + (size_t)BB * DD * DD;         // +131072
  const size_t off_T1   = off_M + (size_t)BB * DD * DD;         // +131072
  const size_t off_T2   = off_T1 + (size_t)BB * HH * KQ * DD;   // +524288
  const size_t off_Mp   = off_T2 + (size_t)BB * HH * KQ * DD;   // +524288
  const size_t off_part = off_Mp + (size_t)BB * 2 * DD * DD;    // +262144

  size_t ws_floats = ws_size / sizeof(float);
  int split = 64;
  while (split > 4 && off_part + (size_t)BB * split * DD * DD > ws_floats) split >>= 1;
  int rowsPer = NN / split;

  float* part = ws + off_part;
  float* G  = ws + off_G;
  float* M  = ws + off_M;
  float* T1 = ws + off_T1;
  float* T2 = ws + off_T2;
  float* Mp = ws + off_Mp;

  gram_partial<<<dim3(split, BB), 256, 0, stream>>>(x, part, rowsPer);
  gram_reduce<<<dim3(16, BB), 256, 0, stream>>>(part, G, split);
  t1_kernel<<<dim3(HH * 4, BB), 256, 0, stream>>>(G, Wk, T1);
  t2_kernel<<<dim3(HH * 4, BB), 256, 0, stream>>>(T1, Wv, T2);
  mpart_kernel<<<dim3(16, BB), 256, 0, stream>>>(T2, Wq, Mp);
  m_reduce<<<dim3(16, BB), 256, 0, stream>>>(Mp, M);
  out_mm<<<dim3(NN / 128, BB), 256, 0, stream>>>(x, M, out);
}

// Round 2
// 74.583 us; speedup vs baseline: 1.7294x; 1.7294x over previous
//
#include <hip/hip_runtime.h>
#include <hip/hip_bf16.h>

#define BB 8
#define NN 8192
#define DD 128
#define HH 8
#define KQ 64

typedef __attribute__((ext_vector_type(8))) short s16x8;
typedef __attribute__((ext_vector_type(4))) float f32x4;
typedef __attribute__((ext_vector_type(4))) unsigned short u16x4;
typedef __attribute__((ext_vector_type(8))) unsigned short u16x8;

// round-to-nearest-even f32 -> bf16 (bit trick)
__device__ __forceinline__ unsigned short bfr(float f) {
  unsigned u = __builtin_bit_cast(unsigned, f);
  u += 0x7fffu + ((u >> 16) & 1u);
  return (unsigned short)(u >> 16);
}

// ---------- Stage 1: partial Gram via MFMA.  part[b][s] = Xc^T Xc ----------
// LDS holds transposed bf16 tile xt[d=128][n=64], XOR-swizzled
// (byte_in_row ^= (d&7)<<4) so 16-row frag reads are 2-way (free).
__global__ __launch_bounds__(256) void gram_mfma(
    const float* __restrict__ x, float* __restrict__ part, int npb, int split) {
  const int s = blockIdx.x, b = blockIdx.y;
  const int t = threadIdx.x, l = t & 63, w = t >> 6;
  __shared__ __align__(16) unsigned short xt[2][128 * 64];
  const float* xb = x + ((size_t)b * NN + (size_t)s * npb) * DD;

  // staging mapping: thread covers d = (t&15)+16i (i<8), n = (t>>4)*4+j (j<4)
  const int sd = t & 15;
  const int sn = (t >> 4) * 4;

  f32x4 acc[4][4];
#pragma unroll
  for (int i = 0; i < 4; ++i)
#pragma unroll
    for (int j = 0; j < 4; ++j) acc[i][j] = (f32x4){0.f, 0.f, 0.f, 0.f};

  float rv[8][4];

  // prologue: load sub-tile 0 to regs, stage into buf 0
#pragma unroll
  for (int i = 0; i < 8; ++i)
#pragma unroll
    for (int j = 0; j < 4; ++j)
      rv[i][j] = xb[(size_t)(sn + j) * DD + sd + 16 * i];

  auto stage = [&](int buf) {
#pragma unroll
    for (int i = 0; i < 8; ++i) {
      const int d = sd + 16 * i;
      u16x4 v;
      v[0] = bfr(rv[i][0]);
      v[1] = bfr(rv[i][1]);
      v[2] = bfr(rv[i][2]);
      v[3] = bfr(rv[i][3]);
      const int boff = (sn * 2) ^ ((d & 7) << 4);
      *(u16x4*)((char*)&xt[buf][0] + d * 128 + boff) = v;
    }
  };
  stage(0);
  __syncthreads();

  const int d1s = (w & 1) * 64, d2s = (w >> 1) * 64;
  const int lr = l & 15, lk = l >> 4;
  const int nsub = npb >> 6;

  for (int sub = 0; sub < nsub; ++sub) {
    const int cur = sub & 1;
    if (sub + 1 < nsub) {
      const float* xs = xb + (size_t)(sub + 1) * 64 * DD;
#pragma unroll
      for (int i = 0; i < 8; ++i)
#pragma unroll
        for (int j = 0; j < 4; ++j)
          rv[i][j] = xs[(size_t)(sn + j) * DD + sd + 16 * i];
    }
#pragma unroll
    for (int kk = 0; kk < 2; ++kk) {
      s16x8 af[4], bv[4];
      const int kb = kk * 64 + lk * 16;  // byte offset of this lane's k-slice
#pragma unroll
      for (int i = 0; i < 4; ++i) {
        const int row = d1s + i * 16 + lr;
        af[i] = *(const s16x8*)((const char*)&xt[cur][0] + row * 128 +
                                (kb ^ ((row & 7) << 4)));
      }
#pragma unroll
      for (int j = 0; j < 4; ++j) {
        const int row = d2s + j * 16 + lr;
        bv[j] = *(const s16x8*)((const char*)&xt[cur][0] + row * 128 +
                                (kb ^ ((row & 7) << 4)));
      }
#pragma unroll
      for (int i = 0; i < 4; ++i)
#pragma unroll
        for (int j = 0; j < 4; ++j)
          acc[i][j] =
              __builtin_amdgcn_mfma_f32_16x16x32_bf16(af[i], bv[j], acc[i][j], 0, 0, 0);
    }
    if (sub + 1 < nsub) stage(cur ^ 1);
    __syncthreads();
  }

  float* g = part + (((size_t)b * split + s) << 14);
#pragma unroll
  for (int i = 0; i < 4; ++i)
#pragma unroll
    for (int j = 0; j < 4; ++j)
#pragma unroll
      for (int r = 0; r < 4; ++r) {
        const int row = d1s + i * 16 + lk * 4 + r;
        const int col = d2s + j * 16 + lr;
        g[row * 128 + col] = acc[i][j][r];
      }
}

// ---------- Stage 2: reduce partials -> G[b] (fp32) ----------
__global__ __launch_bounds__(256) void gram_reduce(
    const float* __restrict__ part, float* __restrict__ G, int split) {
  const int b = blockIdx.y;
  const size_t base = (size_t)blockIdx.x * 1024 + (size_t)threadIdx.x * 4;
  const float* p = part + (size_t)b * split * (DD * DD) + base;
  float4 s = {0.f, 0.f, 0.f, 0.f};
  for (int i = 0; i < split; ++i) {
    float4 v = *(const float4*)(p + (size_t)i * (DD * DD));
    s.x += v.x; s.y += v.y; s.z += v.z; s.w += v.w;
  }
  *(float4*)(G + (size_t)b * (DD * DD) + base) = s;
}

// ---------- Stage 3a: T1[b,h] = Wk[h] @ G[b] ----------
__global__ __launch_bounds__(256) void t1_kernel(
    const float* __restrict__ G, const float* __restrict__ Wk,
    float* __restrict__ T1) {
  const int h = blockIdx.x >> 2, ds = blockIdx.x & 3, b = blockIdx.y;
  const int t = threadIdx.x;
  const int dsbase = ds * 32;
  __shared__ float Wk_t[DD][65];
  __shared__ float Gsl[DD][32];
#pragma unroll
  for (int c = 0; c < 32; ++c) {
    int i = t + c * 256;
    Wk_t[i & 127][i >> 7] = Wk[(size_t)h * KQ * DD + i];
  }
#pragma unroll
  for (int c = 0; c < 4; ++c) {
    int f = t + c * 256;
    int d = f >> 3, c4 = (f & 7) * 4;
    *(float4*)&Gsl[d][c4] =
        *(const float4*)(G + (size_t)b * DD * DD + (size_t)d * DD + dsbase + c4);
  }
  __syncthreads();
  const int k = t >> 2, q = (t & 3) * 8;
  float acc[8];
#pragma unroll
  for (int i = 0; i < 8; ++i) acc[i] = 0.f;
#pragma unroll 4
  for (int d = 0; d < DD; ++d) {
    float wk = Wk_t[d][k];
    float4 g0 = *(const float4*)&Gsl[d][q];
    float4 g1 = *(const float4*)&Gsl[d][q + 4];
    acc[0] = fmaf(wk, g0.x, acc[0]);
    acc[1] = fmaf(wk, g0.y, acc[1]);
    acc[2] = fmaf(wk, g0.z, acc[2]);
    acc[3] = fmaf(wk, g0.w, acc[3]);
    acc[4] = fmaf(wk, g1.x, acc[4]);
    acc[5] = fmaf(wk, g1.y, acc[5]);
    acc[6] = fmaf(wk, g1.z, acc[6]);
    acc[7] = fmaf(wk, g1.w, acc[7]);
  }
  float* dst = T1 + (((size_t)b * HH + h) * KQ + k) * DD + dsbase + q;
  float4 v0 = {acc[0], acc[1], acc[2], acc[3]};
  float4 v1 = {acc[4], acc[5], acc[6], acc[7]};
  ((float4*)dst)[0] = v0;
  ((float4*)dst)[1] = v1;
}

// ---------- Stage 3b: T2[b,h] = T1[b,h] @ Wv[h]^T ----------
__global__ __launch_bounds__(256) void t2_kernel(
    const float* __restrict__ T1, const float* __restrict__ Wv,
    float* __restrict__ T2) {
  const int h = blockIdx.x >> 2, es = blockIdx.x & 3, b = blockIdx.y;
  const int t = threadIdx.x;
  const int ebase = es * 32;
  __shared__ float T1_t[DD][65];
  __shared__ float Wv_t[DD][36];
  const float* t1src = T1 + ((size_t)b * HH + h) * KQ * DD;
#pragma unroll
  for (int c = 0; c < 32; ++c) {
    int i = t + c * 256;
    T1_t[i & 127][i >> 7] = t1src[i];
  }
#pragma unroll
  for (int c = 0; c < 16; ++c) {
    int i = t + c * 256;
    int e = i >> 7, d2 = i & 127;
    Wv_t[d2][e] = Wv[((size_t)h * DD + ebase + e) * DD + d2];
  }
  __syncthreads();
  const int k = t >> 2, q = (t & 3) * 8;
  float acc[8];
#pragma unroll
  for (int i = 0; i < 8; ++i) acc[i] = 0.f;
#pragma unroll 4
  for (int d2 = 0; d2 < DD; ++d2) {
    float t1 = T1_t[d2][k];
    float4 w0 = *(const float4*)&Wv_t[d2][q];
    float4 w1 = *(const float4*)&Wv_t[d2][q + 4];
    acc[0] = fmaf(t1, w0.x, acc[0]);
    acc[1] = fmaf(t1, w0.y, acc[1]);
    acc[2] = fmaf(t1, w0.z, acc[2]);
    acc[3] = fmaf(t1, w0.w, acc[3]);
    acc[4] = fmaf(t1, w1.x, acc[4]);
    acc[5] = fmaf(t1, w1.y, acc[5]);
    acc[6] = fmaf(t1, w1.z, acc[6]);
    acc[7] = fmaf(t1, w1.w, acc[7]);
  }
  float* dst = T2 + (((size_t)b * HH + h) * KQ + k) * DD + ebase + q;
  float4 v0 = {acc[0], acc[1], acc[2], acc[3]};
  float4 v1 = {acc[4], acc[5], acc[6], acc[7]};
  ((float4*)dst)[0] = v0;
  ((float4*)dst)[1] = v1;
}

// ---------- Stage 3c: Mp[b,hs] = Wq_flat[hk-slice]^T @ T2_flat[b][hk-slice] ----------
__global__ __launch_bounds__(256) void mpart_kernel(
    const float* __restrict__ T2, const float* __restrict__ Wq,
    float* __restrict__ Mp) {
  const int es2 = blockIdx.x >> 1, hs = blockIdx.x & 1, b = blockIdx.y;
  const int t = threadIdx.x;
  const int e2 = es2 * 16, hkbase = hs * 256;
  __shared__ float T2s[256][20];
#pragma unroll
  for (int c = 0; c < 4; ++c) {
    int f = t + c * 256;
    int r = f >> 2, c4 = (f & 3) * 4;
    *(float4*)&T2s[r][c4] =
        *(const float4*)(T2 + ((size_t)b * 512 + hkbase + r) * DD + e2 + c4);
  }
  __syncthreads();
  const int d = t >> 1, eh = (t & 1) * 8;
  float acc[8];
#pragma unroll
  for (int i = 0; i < 8; ++i) acc[i] = 0.f;
#pragma unroll 4
  for (int hk = 0; hk < 256; ++hk) {
    float wq = Wq[(size_t)(hkbase + hk) * DD + d];
    float4 a0 = *(const float4*)&T2s[hk][eh];
    float4 a1 = *(const float4*)&T2s[hk][eh + 4];
    acc[0] = fmaf(wq, a0.x, acc[0]);
    acc[1] = fmaf(wq, a0.y, acc[1]);
    acc[2] = fmaf(wq, a0.z, acc[2]);
    acc[3] = fmaf(wq, a0.w, acc[3]);
    acc[4] = fmaf(wq, a1.x, acc[4]);
    acc[5] = fmaf(wq, a1.y, acc[5]);
    acc[6] = fmaf(wq, a1.z, acc[6]);
    acc[7] = fmaf(wq, a1.w, acc[7]);
  }
  float* dst = Mp + ((size_t)b * 2 + hs) * (DD * DD) + (size_t)d * DD + e2 + eh;
  float4 v0 = {acc[0], acc[1], acc[2], acc[3]};
  float4 v1 = {acc[4], acc[5], acc[6], acc[7]};
  ((float4*)dst)[0] = v0;
  ((float4*)dst)[1] = v1;
}

// ---------- Stage 3d: Mt[b][e][d] = bf16(Mp[b][0][d][e] + Mp[b][1][d][e]) ----------
__global__ __launch_bounds__(256) void m_reduce_t(
    const float* __restrict__ Mp, unsigned short* __restrict__ Mt) {
  const int b = blockIdx.y;
  const int base = blockIdx.x * 1024 + threadIdx.x * 4;
  float4 a = *(const float4*)(Mp + ((size_t)b * 2 + 0) * (DD * DD) + base);
  float4 c = *(const float4*)(Mp + ((size_t)b * 2 + 1) * (DD * DD) + base);
  const int d = base >> 7, e0 = base & 127;
  unsigned short* mt = Mt + (size_t)b * (DD * DD);
  mt[(e0 + 0) * DD + d] = bfr(a.x + c.x);
  mt[(e0 + 1) * DD + d] = bfr(a.y + c.y);
  mt[(e0 + 2) * DD + d] = bfr(a.z + c.z);
  mt[(e0 + 3) * DD + d] = bfr(a.w + c.w);
}

// ---------- Stage 4: out[b] = X[b] @ M[b] via MFMA ----------
// A-frags: fp32 x straight from global, converted in-register.
// B: Mt[e][d] staged in LDS with 16-slot XOR swizzle (2-way, free).
__global__ __launch_bounds__(256) void out_mfma(
    const float* __restrict__ x, const unsigned short* __restrict__ Mt,
    float* __restrict__ out) {
  const int b = blockIdx.y, t = threadIdx.x, l = t & 63, w = t >> 6;
  const int r0 = blockIdx.x * 128;
  __shared__ __align__(16) unsigned short mt[DD * DD];
  const unsigned short* msrc = Mt + (size_t)b * (DD * DD);
#pragma unroll
  for (int k = 0; k < 8; ++k) {
    const int c = t + k * 256;      // 16B chunk index (2048 total)
    const int e = c >> 4, slot = c & 15;
    u16x8 v = *(const u16x8*)(msrc + e * DD + slot * 8);
    *(u16x8*)(&mt[e * DD + ((slot ^ (e & 15)) << 3)]) = v;
  }
  __syncthreads();

  const int rw = r0 + (w & 1) * 64, cw = (w >> 1) * 64;
  const int lr = l & 15, lk = l >> 4;
  f32x4 acc[4][4];
#pragma unroll
  for (int i = 0; i < 4; ++i)
#pragma unroll
    for (int j = 0; j < 4; ++j) acc[i][j] = (f32x4){0.f, 0.f, 0.f, 0.f};

  const float* xb = x + (size_t)b * NN * DD;
#pragma unroll
  for (int ks = 0; ks < 4; ++ks) {
    s16x8 af[4];
#pragma unroll
    for (int i = 0; i < 4; ++i) {
      const float* p = xb + (size_t)(rw + i * 16 + lr) * DD + ks * 32 + lk * 8;
      float4 v0 = *(const float4*)p;
      float4 v1 = *(const float4*)(p + 4);
      s16x8 a;
      a[0] = (short)bfr(v0.x); a[1] = (short)bfr(v0.y);
      a[2] = (short)bfr(v0.z); a[3] = (short)bfr(v0.w);
      a[4] = (short)bfr(v1.x); a[5] = (short)bfr(v1.y);
      a[6] = (short)bfr(v1.z); a[7] = (short)bfr(v1.w);
      af[i] = a;
    }
    s16x8 bv[4];
#pragma unroll
    for (int j = 0; j < 4; ++j) {
      const int e = cw + j * 16 + lr;
      const int slot = ks * 4 + lk;
      bv[j] = *(const s16x8*)(&mt[e * DD + ((slot ^ (e & 15)) << 3)]);
    }
#pragma unroll
    for (int i = 0; i < 4; ++i)
#pragma unroll
      for (int j = 0; j < 4; ++j)
        acc[i][j] =
            __builtin_amdgcn_mfma_f32_16x16x32_bf16(af[i], bv[j], acc[i][j], 0, 0, 0);
  }

  float* ob = out + (size_t)b * NN * DD;
#pragma unroll
  for (int i = 0; i < 4; ++i)
#pragma unroll
    for (int j = 0; j < 4; ++j)
#pragma unroll
      for (int r = 0; r < 4; ++r) {
        const int row = rw + i * 16 + lk * 4 + r;
        const int col = cw + j * 16 + lr;
        ob[(size_t)row * DD + col] = acc[i][j][r];
      }
}

extern "C" void kernel_launch(void* const* d_in, const int* in_sizes, int n_in,
                              void* d_out, int out_size, void* d_ws, size_t ws_size,
                              hipStream_t stream) {
  const float* x  = (const float*)d_in[0];
  const float* Wk = (const float*)d_in[1];
  const float* Wq = (const float*)d_in[2];
  const float* Wv = (const float*)d_in[3];
  float* out = (float*)d_out;
  float* ws  = (float*)d_ws;

  const size_t off_G    = 0;                          // 131072 floats
  const size_t off_T1   = off_G + (size_t)BB * DD * DD;
  const size_t off_T2   = off_T1 + (size_t)BB * HH * KQ * DD;
  const size_t off_Mp   = off_T2 + (size_t)BB * HH * KQ * DD;
  const size_t off_Mt   = off_Mp + (size_t)BB * 2 * DD * DD;   // bf16: 131072 u16 = 65536 float slots
  const size_t off_part = off_Mt + (size_t)BB * DD * DD / 2;

  size_t ws_floats = ws_size / sizeof(float);
  int split = 32;
  while (split > 1 && off_part + (size_t)BB * split * DD * DD > ws_floats) split >>= 1;
  int npb = NN / split;

  float* G    = ws + off_G;
  float* T1   = ws + off_T1;
  float* T2   = ws + off_T2;
  float* Mp   = ws + off_Mp;
  unsigned short* Mt = (unsigned short*)(ws + off_Mt);
  float* part = ws + off_part;

  gram_mfma<<<dim3(split, BB), 256, 0, stream>>>(x, part, npb, split);
  gram_reduce<<<dim3(16, BB), 256, 0, stream>>>(part, G, split);
  t1_kernel<<<dim3(HH * 4, BB), 256, 0, stream>>>(G, Wk, T1);
  t2_kernel<<<dim3(HH * 4, BB), 256, 0, stream>>>(T1, Wv, T2);
  mpart_kernel<<<dim3(16, BB), 256, 0, stream>>>(T2, Wq, Mp);
  m_reduce_t<<<dim3(16, BB), 256, 0, stream>>>(Mp, Mt);
  out_mfma<<<dim3(NN / 128, BB), 256, 0, stream>>>(x, Mt, out);
}

// Round 3
// 53.151 us; speedup vs baseline: 2.4267x; 1.4032x over previous
//
#include <hip/hip_runtime.h>
#include <hip/hip_bf16.h>

#define BB 8
#define NN 8192
#define DD 128
#define HH 8
#define KQ 64
#define SPLIT 32
#define NPB (NN / SPLIT)   // 256 rows per gram block

typedef __attribute__((ext_vector_type(8))) short s16x8;
typedef __attribute__((ext_vector_type(4))) float f32x4;
typedef __attribute__((ext_vector_type(4))) unsigned short u16x4;
typedef __attribute__((ext_vector_type(8))) unsigned short u16x8;

// round-to-nearest-even f32 -> bf16 (bit trick)
__device__ __forceinline__ unsigned short bfr(float f) {
  unsigned u = __builtin_bit_cast(unsigned, f);
  u += 0x7fffu + ((u >> 16) & 1u);
  return (unsigned short)(u >> 16);
}

// ---------- Stage 0: weight prep (bf16 conversion, Wq transpose) ----------
// grid 200 blocks x 256:
//   [0,64)    Wk  -> Wkbf[h][k][d]
//   [64,192)  Wv  -> Wvbf[h][e][d2]
//   [192,200) Wq  -> Wqt[h][d][k]  (transposed)
__global__ __launch_bounds__(256) void prep(
    const float* __restrict__ Wk, const float* __restrict__ Wq,
    const float* __restrict__ Wv, unsigned short* __restrict__ Wkbf,
    unsigned short* __restrict__ Wvbf, unsigned short* __restrict__ Wqt) {
  const int bx = blockIdx.x, t = threadIdx.x;
  if (bx < 64) {
    const int i = bx * 1024 + t * 4;
    float4 v = *(const float4*)(Wk + i);
    u16x4 o = {bfr(v.x), bfr(v.y), bfr(v.z), bfr(v.w)};
    *(u16x4*)(Wkbf + i) = o;
  } else if (bx < 192) {
    const int i = (bx - 64) * 1024 + t * 4;
    float4 v = *(const float4*)(Wv + i);
    u16x4 o = {bfr(v.x), bfr(v.y), bfr(v.z), bfr(v.w)};
    *(u16x4*)(Wvbf + i) = o;
  } else {
    const int h = bx - 192;
    const int d4 = (t & 31) * 4;
#pragma unroll
    for (int p = 0; p < 8; ++p) {
      const int k = (t >> 5) + p * 8;
      float4 v = *(const float4*)(Wq + (size_t)h * 8192 + k * DD + d4);
      unsigned short* dst = Wqt + (size_t)h * 8192;
      dst[(d4 + 0) * KQ + k] = bfr(v.x);
      dst[(d4 + 1) * KQ + k] = bfr(v.y);
      dst[(d4 + 2) * KQ + k] = bfr(v.z);
      dst[(d4 + 3) * KQ + k] = bfr(v.w);
    }
  }
}

// ---------- Stage 1: partial Gram via MFMA (512 threads, 8 waves) ----------
// LDS xt[d=128][n=64] bf16, swizzled: slot(=n>>3) ^= (d&7).
__global__ __launch_bounds__(512) void gram_mfma(
    const float* __restrict__ x, float* __restrict__ part) {
  const int s = blockIdx.x, b = blockIdx.y;
  const int t = threadIdx.x, l = t & 63, w = t >> 6;
  __shared__ __align__(16) unsigned short xt[2][128 * 64];
  const float* xb = x + ((size_t)b * NN + (size_t)s * NPB) * DD;

  // staging: thread covers d = sd+16i (i<8), n = sn, sn+1
  const int sd = t & 15;
  const int sn = (t >> 4) * 2;

  f32x4 acc[4][2];
#pragma unroll
  for (int i = 0; i < 4; ++i)
#pragma unroll
    for (int j = 0; j < 2; ++j) acc[i][j] = (f32x4){0.f, 0.f, 0.f, 0.f};

  float rv[8][2];
  auto load = [&](int sub) {
    const float* xs = xb + (size_t)sub * 64 * DD;
#pragma unroll
    for (int i = 0; i < 8; ++i)
#pragma unroll
      for (int j = 0; j < 2; ++j)
        rv[i][j] = xs[(size_t)(sn + j) * DD + sd + 16 * i];
  };
  auto stage = [&](int buf) {
    const int slot = sn >> 3;
#pragma unroll
    for (int i = 0; i < 8; ++i) {
      const int d = sd + 16 * i;
      unsigned v = (unsigned)bfr(rv[i][0]) | ((unsigned)bfr(rv[i][1]) << 16);
      char* dst = (char*)&xt[buf][0] + d * 128 +
                  (((slot ^ (d & 7)) << 4) | ((sn & 7) * 2));
      *(unsigned*)dst = v;
    }
  };

  load(0);
  stage(0);
  __syncthreads();

  const int d1s = (w & 1) * 64, d2s = (w >> 1) * 32;
  const int lr = l & 15, lk = l >> 4;
  const int nsub = NPB / 64;

  for (int sub = 0; sub < nsub; ++sub) {
    const int cur = sub & 1;
    if (sub + 1 < nsub) load(sub + 1);
#pragma unroll
    for (int kk = 0; kk < 2; ++kk) {
      s16x8 af[4], bv[2];
      const int kb = kk * 64 + lk * 16;
#pragma unroll
      for (int i = 0; i < 4; ++i) {
        const int row = d1s + i * 16 + lr;
        af[i] = *(const s16x8*)((const char*)&xt[cur][0] + row * 128 +
                                (kb ^ ((row & 7) << 4)));
      }
#pragma unroll
      for (int j = 0; j < 2; ++j) {
        const int row = d2s + j * 16 + lr;
        bv[j] = *(const s16x8*)((const char*)&xt[cur][0] + row * 128 +
                                (kb ^ ((row & 7) << 4)));
      }
#pragma unroll
      for (int i = 0; i < 4; ++i)
#pragma unroll
        for (int j = 0; j < 2; ++j)
          acc[i][j] =
              __builtin_amdgcn_mfma_f32_16x16x32_bf16(af[i], bv[j], acc[i][j], 0, 0, 0);
    }
    if (sub + 1 < nsub) stage(cur ^ 1);
    __syncthreads();
  }

  float* g = part + (((size_t)b * SPLIT + s) << 14);
#pragma unroll
  for (int i = 0; i < 4; ++i)
#pragma unroll
    for (int j = 0; j < 2; ++j)
#pragma unroll
      for (int r = 0; r < 4; ++r) {
        const int row = d1s + i * 16 + lk * 4 + r;
        const int col = d2s + j * 16 + lr;
        g[row * 128 + col] = acc[i][j][r];
      }
}

// ---------- Stage 2: reduce partials -> Gbf[b] (bf16) ----------
__global__ __launch_bounds__(256) void gram_reduce(
    const float* __restrict__ part, unsigned short* __restrict__ Gbf) {
  const int b = blockIdx.y;
  const int idx = blockIdx.x * 1024 + threadIdx.x * 4;
  const float* p = part + ((size_t)b * SPLIT << 14) + idx;
  float4 s = {0.f, 0.f, 0.f, 0.f};
  for (int i = 0; i < SPLIT; ++i) {
    float4 v = *(const float4*)(p + ((size_t)i << 14));
    s.x += v.x; s.y += v.y; s.z += v.z; s.w += v.w;
  }
  u16x4 o = {bfr(s.x), bfr(s.y), bfr(s.z), bfr(s.w)};
  *(u16x4*)(Gbf + ((size_t)b << 14) + idx) = o;
}

// ---------- Stage 3 (fused): Mp[b,h] = (Wq^T (Wk G Wv^T))^T contribution ----------
// per-(b,h) block, 256 threads / 4 waves, three chained MFMA matmuls.
__global__ __launch_bounds__(256) void middle_fused(
    const unsigned short* __restrict__ Gbf, const unsigned short* __restrict__ Wkbf,
    const unsigned short* __restrict__ Wvbf, const unsigned short* __restrict__ Wqt,
    float* __restrict__ Mp) {
  const int b = blockIdx.x >> 3, h = blockIdx.x & 7;
  const int t = threadIdx.x, l = t & 63, w = t >> 6;
  const int lr = l & 15, lk = l >> 4;
  __shared__ __align__(16) unsigned short Gs[128 * 128];  // 32 KB, 16-slot swz
  __shared__ __align__(16) unsigned short T1s[64 * 128];  // 16 KB, 16-slot swz
  __shared__ __align__(16) unsigned short T2t[128 * 64];  // 16 KB, 8-slot swz

  // stage Gbf -> Gs (slot ^= row&15)
  const unsigned short* gsrc = Gbf + ((size_t)b << 14);
#pragma unroll
  for (int c8 = 0; c8 < 8; ++c8) {
    const int c = t + c8 * 256;
    const int row = c >> 4, slot = c & 15;
    u16x8 v = *(const u16x8*)(gsrc + row * 128 + slot * 8);
    *(u16x8*)(&Gs[row * 128 + ((slot ^ (row & 15)) << 3)]) = v;
  }
  __syncthreads();

  // ---- stage A: T1 = Wk[h] @ G  (64x128), wave w owns row-tile w ----
  const unsigned short* wk = Wkbf + ((size_t)h << 13);
  s16x8 aw[4];
#pragma unroll
  for (int ks = 0; ks < 4; ++ks)
    aw[ks] = *(const s16x8*)(wk + ((w * 16 + lr) << 7) + ks * 32 + lk * 8);
  f32x4 accA[8];
#pragma unroll
  for (int j = 0; j < 8; ++j) accA[j] = (f32x4){0.f, 0.f, 0.f, 0.f};
#pragma unroll
  for (int nj = 0; nj < 8; ++nj)
#pragma unroll
    for (int ks = 0; ks < 4; ++ks) {
      const int row = nj * 16 + lr;  // G row d2 (symmetry: col read = row read)
      const int slot = (ks * 4 + lk) ^ (row & 15);
      s16x8 bfrag = *(const s16x8*)(&Gs[(row << 7) + (slot << 3)]);
      accA[nj] = __builtin_amdgcn_mfma_f32_16x16x32_bf16(aw[ks], bfrag, accA[nj], 0, 0, 0);
    }
  // write T1s[k_out][d2] bf16 swizzled
#pragma unroll
  for (int nj = 0; nj < 8; ++nj)
#pragma unroll
    for (int r = 0; r < 4; ++r) {
      const int row = w * 16 + lk * 4 + r;
      const int col = nj * 16 + lr;
      const int slot = (col >> 3) ^ (row & 15);
      T1s[(row << 7) + (slot << 3) + (col & 7)] = bfr(accA[nj][r]);
    }
  __syncthreads();

  // ---- stage B: T2 = T1 @ Wv^T  (64x128), wave w owns row-tile w ----
  s16x8 a2[4];
#pragma unroll
  for (int ks = 0; ks < 4; ++ks) {
    const int row = w * 16 + lr;
    const int slot = (ks * 4 + lk) ^ (row & 15);
    a2[ks] = *(const s16x8*)(&T1s[(row << 7) + (slot << 3)]);
  }
  const unsigned short* wv = Wvbf + ((size_t)h << 14);
  f32x4 accB[8];
#pragma unroll
  for (int j = 0; j < 8; ++j) accB[j] = (f32x4){0.f, 0.f, 0.f, 0.f};
#pragma unroll
  for (int nj = 0; nj < 8; ++nj)
#pragma unroll
    for (int ks = 0; ks < 4; ++ks) {
      s16x8 bfrag = *(const s16x8*)(wv + (((size_t)(nj * 16 + lr)) << 7) + ks * 32 + lk * 8);
      accB[nj] = __builtin_amdgcn_mfma_f32_16x16x32_bf16(a2[ks], bfrag, accB[nj], 0, 0, 0);
    }
  // write T2t[e][k] bf16 (transposed), 8-slot swz
#pragma unroll
  for (int nj = 0; nj < 8; ++nj)
#pragma unroll
    for (int r = 0; r < 4; ++r) {
      const int e = nj * 16 + lr;
      const int k = w * 16 + lk * 4 + r;
      const int slot = (k >> 3) ^ (e & 7);
      T2t[(e << 6) + (slot << 3) + (k & 7)] = bfr(accB[nj][r]);
    }
  __syncthreads();

  // ---- stage C: M^T contrib = T2^T @ Wq  (128x128), wave w owns e-tiles 2w,2w+1 ----
  const unsigned short* wq = Wqt + ((size_t)h << 13);
  float* mp = Mp + (((size_t)(b * 8 + h)) << 14);
#pragma unroll
  for (int p = 0; p < 2; ++p) {
    s16x8 a3[2];
#pragma unroll
    for (int ks = 0; ks < 2; ++ks) {
      const int row = (2 * w + p) * 16 + lr;
      const int slot = (ks * 4 + lk) ^ (row & 7);
      a3[ks] = *(const s16x8*)(&T2t[(row << 6) + (slot << 3)]);
    }
    f32x4 accC[8];
#pragma unroll
    for (int j = 0; j < 8; ++j) accC[j] = (f32x4){0.f, 0.f, 0.f, 0.f};
#pragma unroll
    for (int nj = 0; nj < 8; ++nj)
#pragma unroll
      for (int ks = 0; ks < 2; ++ks) {
        s16x8 bfrag = *(const s16x8*)(wq + ((nj * 16 + lr) << 6) + ks * 32 + lk * 8);
        accC[nj] = __builtin_amdgcn_mfma_f32_16x16x32_bf16(a3[ks], bfrag, accC[nj], 0, 0, 0);
      }
#pragma unroll
    for (int nj = 0; nj < 8; ++nj)
#pragma unroll
      for (int r = 0; r < 4; ++r) {
        const int row = (2 * w + p) * 16 + lk * 4 + r;
        const int col = nj * 16 + lr;
        mp[(row << 7) + col] = accC[nj][r];
      }
  }
}

// ---------- Stage 3d: Mt[b][e][d] = bf16( sum_h Mp[b][h][e][d] ) ----------
__global__ __launch_bounds__(256) void m_reduce_t(
    const float* __restrict__ Mp, unsigned short* __restrict__ Mt) {
  const int b = blockIdx.y;
  const int idx = blockIdx.x * 1024 + threadIdx.x * 4;
  float4 s = {0.f, 0.f, 0.f, 0.f};
#pragma unroll
  for (int h = 0; h < 8; ++h) {
    float4 v = *(const float4*)(Mp + (((size_t)(b * 8 + h)) << 14) + idx);
    s.x += v.x; s.y += v.y; s.z += v.z; s.w += v.w;
  }
  u16x4 o = {bfr(s.x), bfr(s.y), bfr(s.z), bfr(s.w)};
  *(u16x4*)(Mt + ((size_t)b << 14) + idx) = o;
}

// ---------- Stage 4: out[b] = X[b] @ M[b] via MFMA ----------
__global__ __launch_bounds__(256) void out_mfma(
    const float* __restrict__ x, const unsigned short* __restrict__ Mt,
    float* __restrict__ out) {
  const int b = blockIdx.y, t = threadIdx.x, l = t & 63, w = t >> 6;
  const int r0 = blockIdx.x * 128;
  __shared__ __align__(16) unsigned short mt[DD * DD];
  const unsigned short* msrc = Mt + (size_t)b * (DD * DD);
#pragma unroll
  for (int k = 0; k < 8; ++k) {
    const int c = t + k * 256;
    const int e = c >> 4, slot = c & 15;
    u16x8 v = *(const u16x8*)(msrc + e * DD + slot * 8);
    *(u16x8*)(&mt[e * DD + ((slot ^ (e & 15)) << 3)]) = v;
  }
  __syncthreads();

  const int rw = r0 + (w & 1) * 64, cw = (w >> 1) * 64;
  const int lr = l & 15, lk = l >> 4;
  f32x4 acc[4][4];
#pragma unroll
  for (int i = 0; i < 4; ++i)
#pragma unroll
    for (int j = 0; j < 4; ++j) acc[i][j] = (f32x4){0.f, 0.f, 0.f, 0.f};

  const float* xb = x + (size_t)b * NN * DD;
#pragma unroll
  for (int ks = 0; ks < 4; ++ks) {
    s16x8 af[4];
#pragma unroll
    for (int i = 0; i < 4; ++i) {
      const float* p = xb + (size_t)(rw + i * 16 + lr) * DD + ks * 32 + lk * 8;
      float4 v0 = *(const float4*)p;
      float4 v1 = *(const float4*)(p + 4);
      s16x8 a;
      a[0] = (short)bfr(v0.x); a[1] = (short)bfr(v0.y);
      a[2] = (short)bfr(v0.z); a[3] = (short)bfr(v0.w);
      a[4] = (short)bfr(v1.x); a[5] = (short)bfr(v1.y);
      a[6] = (short)bfr(v1.z); a[7] = (short)bfr(v1.w);
      af[i] = a;
    }
    s16x8 bv[4];
#pragma unroll
    for (int j = 0; j < 4; ++j) {
      const int e = cw + j * 16 + lr;
      const int slot = ks * 4 + lk;
      bv[j] = *(const s16x8*)(&mt[e * DD + ((slot ^ (e & 15)) << 3)]);
    }
#pragma unroll
    for (int i = 0; i < 4; ++i)
#pragma unroll
      for (int j = 0; j < 4; ++j)
        acc[i][j] =
            __builtin_amdgcn_mfma_f32_16x16x32_bf16(af[i], bv[j], acc[i][j], 0, 0, 0);
  }

  float* ob = out + (size_t)b * NN * DD;
#pragma unroll
  for (int i = 0; i < 4; ++i)
#pragma unroll
    for (int j = 0; j < 4; ++j)
#pragma unroll
      for (int r = 0; r < 4; ++r) {
        const int row = rw + i * 16 + lk * 4 + r;
        const int col = cw + j * 16 + lr;
        ob[(size_t)row * DD + col] = acc[i][j][r];
      }
}

extern "C" void kernel_launch(void* const* d_in, const int* in_sizes, int n_in,
                              void* d_out, int out_size, void* d_ws, size_t ws_size,
                              hipStream_t stream) {
  const float* x  = (const float*)d_in[0];
  const float* Wk = (const float*)d_in[1];
  const float* Wq = (const float*)d_in[2];
  const float* Wv = (const float*)d_in[3];
  float* out = (float*)d_out;
  float* ws  = (float*)d_ws;

  // workspace layout (float slots, all 16B-aligned)
  const size_t off_part = 0;                                   // 8*32*16384 = 4194304
  const size_t off_Mp   = off_part + (size_t)BB * SPLIT * DD * DD;  // 1048576
  const size_t off_Gbf  = off_Mp + (size_t)BB * HH * DD * DD;       // u16: 131072 -> 65536 slots
  const size_t off_Mt   = off_Gbf + (size_t)BB * DD * DD / 2;
  const size_t off_Wkbf = off_Mt + (size_t)BB * DD * DD / 2;
  const size_t off_Wvbf = off_Wkbf + (size_t)HH * KQ * DD / 2;
  const size_t off_Wqt  = off_Wvbf + (size_t)HH * DD * DD / 2;

  float* part = ws + off_part;
  float* Mp   = ws + off_Mp;
  unsigned short* Gbf  = (unsigned short*)(ws + off_Gbf);
  unsigned short* Mt   = (unsigned short*)(ws + off_Mt);
  unsigned short* Wkbf = (unsigned short*)(ws + off_Wkbf);
  unsigned short* Wvbf = (unsigned short*)(ws + off_Wvbf);
  unsigned short* Wqt  = (unsigned short*)(ws + off_Wqt);

  gram_mfma<<<dim3(SPLIT, BB), 512, 0, stream>>>(x, part);
  prep<<<200, 256, 0, stream>>>(Wk, Wq, Wv, Wkbf, Wvbf, Wqt);
  gram_reduce<<<dim3(16, BB), 256, 0, stream>>>(part, Gbf);
  middle_fused<<<64, 256, 0, stream>>>(Gbf, Wkbf, Wvbf, Wqt, Mp);
  m_reduce_t<<<dim3(16, BB), 256, 0, stream>>>(Mp, Mt);
  out_mfma<<<dim3(NN / 128, BB), 256, 0, stream>>>(x, Mt, out);
}